// Round 5
// baseline (247.772 us; speedup 1.0000x reference)
//
#include <hip/hip_runtime.h>
#include <cmath>

// SSM forward, round 5: fragment-major LDS GEMM (conflict-free ds_read_b128 via
// pre-permuted global_load_lds source), dbuf 1-barrier/K-step, XCD swizzle.

#define SEQ    1024
#define BATCH  2
#define DMODEL 1024
#define DINNER 2048
#define DSTATE 16
#define NTOK   (BATCH * SEQ)
#define NCHUNK 32
#define CLEN   32
#define NEXT   2112  // DINNER + 16 + 16 + 32 pad (64-multiple)

typedef __attribute__((ext_vector_type(8))) short short8;
typedef __attribute__((ext_vector_type(4))) float f32x4;

__device__ __forceinline__ unsigned short f2bf(float f) {
  unsigned int u = __float_as_uint(f);
  unsigned int r = (u + 0x7fffu + ((u >> 16) & 1u)) >> 16;
  return (unsigned short)r;
}

__device__ __forceinline__ float softplus_f(float x) {
  return (x > 20.f) ? x : log1pf(__expf(x));
}

__device__ __forceinline__ void gload_lds16(const void* g, void* l) {
  __builtin_amdgcn_global_load_lds(
      (const __attribute__((address_space(1))) unsigned int*)g,
      (__attribute__((address_space(3))) unsigned int*)l, 16, 0, 0);
}

__global__ __launch_bounds__(256) void init_aneg_k(const float* __restrict__ A_log,
                                                   float* __restrict__ Aneg) {
  int i = blockIdx.x * 256 + threadIdx.x;
  Aneg[i] = -__expf(A_log[i]);
}

// W[K][N] f32 -> Wt[N][K] bf16, 32x32 LDS tiles.
__global__ void transpose_cvt_k(const float* __restrict__ W, unsigned short* __restrict__ Wt,
                                int K, int N) {
  __shared__ float tile[32][33];
  int k0 = blockIdx.y * 32, n0 = blockIdx.x * 32;
  int tx = threadIdx.x, ty = threadIdx.y;  // 32 x 8
#pragma unroll
  for (int i = 0; i < 32; i += 8)
    tile[ty + i][tx] = W[(size_t)(k0 + ty + i) * N + n0 + tx];
  __syncthreads();
#pragma unroll
  for (int i = 0; i < 32; i += 8)
    Wt[(size_t)(n0 + ty + i) * K + k0 + tx] = f2bf(tile[tx][ty + i]);
}

// Combined dt|B|C transposed weight: Wt[NEXT][DINNER] bf16.
__global__ void build_w2t_k(const float* __restrict__ dt_w, const float* __restrict__ B_w,
                            const float* __restrict__ C_w, unsigned short* __restrict__ Wt) {
  __shared__ float tile[32][33];
  int k0 = blockIdx.x * 32, n0 = blockIdx.y * 32;
  int tx = threadIdx.x, ty = threadIdx.y;  // 32 x 8
  if (n0 < DINNER) {
#pragma unroll
    for (int i = 0; i < 32; i += 8)
      tile[ty + i][tx] = dt_w[(size_t)(k0 + ty + i) * DINNER + n0 + tx];
    __syncthreads();
#pragma unroll
    for (int i = 0; i < 32; i += 8)
      Wt[(size_t)(n0 + ty + i) * DINNER + k0 + tx] = f2bf(tile[tx][ty + i]);
  } else {
#pragma unroll
    for (int i = 0; i < 32; i += 8) {
      int n = n0 + ty + i;
      float v = 0.f;
      if (n < DINNER + 16) v = B_w[(size_t)(k0 + tx) * DSTATE + (n - DINNER)];
      else if (n < DINNER + 32) v = C_w[(size_t)(k0 + tx) * DSTATE + (n - DINNER - 16)];
      Wt[(size_t)n * DINNER + k0 + tx] = f2bf(v);
    }
  }
}

__global__ __launch_bounds__(256) void rmsnorm_k(const float* __restrict__ x,
                                                 const float* __restrict__ w,
                                                 unsigned short* __restrict__ xnbf) {
  int row = blockIdx.x, tid = threadIdx.x;
  const float4 v = *(const float4*)(x + (size_t)row * DMODEL + tid * 4);
  float ss = v.x * v.x + v.y * v.y + v.z * v.z + v.w * v.w;
#pragma unroll
  for (int off = 32; off > 0; off >>= 1) ss += __shfl_down(ss, off);
  __shared__ float red[4];
  if ((tid & 63) == 0) red[tid >> 6] = ss;
  __syncthreads();
  float tot = red[0] + red[1] + red[2] + red[3];
  float scale = rsqrtf(tot * (1.0f / DMODEL) + 1e-6f);
  const float4 wv = *(const float4*)(w + tid * 4);
  ushort4 o;
  o.x = f2bf(v.x * scale * wv.x);
  o.y = f2bf(v.y * scale * wv.y);
  o.z = f2bf(v.z * scale * wv.z);
  o.w = f2bf(v.w * scale * wv.w);
  *(ushort4*)(xnbf + (size_t)row * DMODEL + tid * 4) = o;
}

// C = A[M,K](bf16) @ Bt[N,K](bf16)^T, f32 out. BMxBN tile, BK=32, 4 waves (2x2).
// LDS is FRAGMENT-MAJOR: each 1KB subtile = one 16-row x 32-k MFMA operand in lane
// order (lane l holds row l&15, k (l>>4)*8). Staged by global_load_lds with the
// per-lane GLOBAL address permuted to fragment order (LDS dest stays linear), so
// the ds_read_b128 at subtile_base + lane*16B is fully contiguous = conflict-free.
// MODE 0: plain C. MODE 2: dt|B|C combined epilogue.
template <int BM, int BN, int MODE>
__global__ __launch_bounds__(256) void gemm_bf16_t(const unsigned short* __restrict__ A,
                                                   const unsigned short* __restrict__ Bt,
                                                   float* __restrict__ C,
                                                   int M, int N, int K, int ldc,
                                                   const float* __restrict__ bias,
                                                   float* __restrict__ Bm,
                                                   float* __restrict__ Cm) {
  constexpr int WTM = BM / 2, WTN = BN / 2;
  constexpr int FM = WTM / 16, FN = WTN / 16;
  constexpr int ASUB = BM / 16, BSUB = BN / 16;
  __shared__ __align__(16) unsigned short Abuf[2][BM * 32];
  __shared__ __align__(16) unsigned short Bbuf[2][BN * 32];
  const int tid = threadIdx.x;
  const int wave = tid >> 6, lane = tid & 63;

  // XCD-aware swizzle (total wg count is a multiple of 8).
  const int gx = gridDim.x;
  int lin = blockIdx.y * gx + blockIdx.x;
  int nwg = gx * gridDim.y;
  int swz = (lin & 7) * (nwg >> 3) + (lin >> 3);
  const int bm = (swz / gx) * BM, bn = (swz % gx) * BN;

  const int wm = wave >> 1, wn = wave & 1;
  // fragment-order source coordinates for this lane:
  const int frow = lane & 15, fk = (lane >> 4) * 8;
  const unsigned short* Ag = A + (size_t)(bm + frow) * K + fk;
  const unsigned short* Bg = Bt + (size_t)(bn + frow) * K + fk;

  auto stage = [&](int buf, int k0) {
#pragma unroll
    for (int s = wave; s < ASUB; s += 4)
      gload_lds16(Ag + (size_t)s * 16 * K + k0, &Abuf[buf][s * 512]);
#pragma unroll
    for (int s = wave; s < BSUB; s += 4)
      gload_lds16(Bg + (size_t)s * 16 * K + k0, &Bbuf[buf][s * 512]);
  };

  f32x4 acc[FM][FN] = {};
  const int nt = K / 32;
  stage(0, 0);
  __syncthreads();
  int cur = 0;
  for (int t = 0; t < nt; ++t) {
    if (t + 1 < nt) stage(cur ^ 1, (t + 1) * 32);
    short8 af[FM], bfr[FN];
#pragma unroll
    for (int m = 0; m < FM; ++m)
      af[m] = *(const short8*)&Abuf[cur][(wm * FM + m) * 512 + (lane << 3)];
#pragma unroll
    for (int n = 0; n < FN; ++n)
      bfr[n] = *(const short8*)&Bbuf[cur][(wn * FN + n) * 512 + (lane << 3)];
#pragma unroll
    for (int m = 0; m < FM; ++m)
#pragma unroll
      for (int n = 0; n < FN; ++n)
        acc[m][n] = __builtin_amdgcn_mfma_f32_16x16x32_bf16(af[m], bfr[n], acc[m][n], 0, 0, 0);
    __syncthreads();  // drains stage(t+1) vmem + guards dbuf WAR
    cur ^= 1;
  }

  const int rbase = bm + wm * WTM + (lane >> 4) * 4;
  const int cbase = bn + wn * WTN + (lane & 15);
#pragma unroll
  for (int m = 0; m < FM; ++m)
#pragma unroll
    for (int n = 0; n < FN; ++n) {
      int col = cbase + n * 16;
#pragma unroll
      for (int r = 0; r < 4; ++r) {
        int row = rbase + m * 16 + r;
        float v = acc[m][n][r];
        if (MODE == 0) {
          C[(size_t)row * ldc + col] = v;
        } else {  // MODE 2 (dt | B | C combined)
          if (col < DINNER)
            C[(size_t)row * DINNER + col] = softplus_f(v + bias[col]);
          else if (col < DINNER + 16)
            Bm[(size_t)row * DSTATE + (col - DINNER)] = v;
          else if (col < DINNER + 32)
            Cm[(size_t)row * DSTATE + (col - DINNER - 16)] = v;
        }
      }
    }
}

// Fused: x_inner = a * silu(g), then causal depthwise conv width 4. 8 t per thread.
__global__ __launch_bounds__(256) void siluconv_k(const float* __restrict__ xg,
                                                  const float* __restrict__ w,
                                                  float* __restrict__ xc,
                                                  unsigned short* __restrict__ xcbf) {
  int idx = blockIdx.x * 256 + threadIdx.x;
  int d4 = (idx & 511) << 2;
  int tc = (idx >> 9) & 127;
  int b = idx >> 16;
  float4 w0 = *(const float4*)(w + (d4 + 0) * 4);
  float4 w1 = *(const float4*)(w + (d4 + 1) * 4);
  float4 w2 = *(const float4*)(w + (d4 + 2) * 4);
  float4 w3 = *(const float4*)(w + (d4 + 3) * 4);
  const float wj0[4] = {w0.x, w0.y, w0.z, w0.w};
  const float wj1[4] = {w1.x, w1.y, w1.z, w1.w};
  const float wj2[4] = {w2.x, w2.y, w2.z, w2.w};
  const float wj3[4] = {w3.x, w3.y, w3.z, w3.w};
  const float* pa = xg + (size_t)b * SEQ * (2 * DINNER) + d4;
  const float* pg = pa + DINNER;
  int t0 = tc * 8;
  float4 sA = {0.f, 0.f, 0.f, 0.f}, sB = sA, sC = sA;
  auto gated = [&](int t) {
    float4 a = *(const float4*)(pa + (size_t)t * (2 * DINNER));
    float4 g = *(const float4*)(pg + (size_t)t * (2 * DINNER));
    float4 r;
    r.x = a.x * (g.x / (1.f + __expf(-g.x)));
    r.y = a.y * (g.y / (1.f + __expf(-g.y)));
    r.z = a.z * (g.z / (1.f + __expf(-g.z)));
    r.w = a.w * (g.w / (1.f + __expf(-g.w)));
    return r;
  };
  if (t0 > 0) {
    sA = gated(t0 - 3);
    sB = gated(t0 - 2);
    sC = gated(t0 - 1);
  }
#pragma unroll
  for (int j = 0; j < 8; ++j) {
    int t = t0 + j;
    float4 sD = gated(t);
    float4 o;
    o.x = sA.x * wj0[0] + sB.x * wj0[1] + sC.x * wj0[2] + sD.x * wj0[3];
    o.y = sA.y * wj1[0] + sB.y * wj1[1] + sC.y * wj1[2] + sD.y * wj1[3];
    o.z = sA.z * wj2[0] + sB.z * wj2[1] + sC.z * wj2[2] + sD.z * wj2[3];
    o.w = sA.w * wj3[0] + sB.w * wj3[1] + sC.w * wj3[2] + sD.w * wj3[3];
    size_t ro = ((size_t)(b * SEQ + t)) * DINNER + d4;
    *(float4*)(xc + ro) = o;
    ushort4 ob = {f2bf(o.x), f2bf(o.y), f2bf(o.z), f2bf(o.w)};
    *(ushort4*)(xcbf + ro) = ob;
    sA = sB; sB = sC; sC = sD;
  }
}

__global__ __launch_bounds__(256) void scan_local_k(const float* __restrict__ dt,
                                                    const float* __restrict__ xc,
                                                    const float* __restrict__ Bm,
                                                    const float* __restrict__ A,
                                                    float* __restrict__ hfin,
                                                    float* __restrict__ P) {
  int d = blockIdx.x * 256 + threadIdx.x;
  int c = blockIdx.y, b = blockIdx.z;
  float a[DSTATE], h[DSTATE];
#pragma unroll
  for (int s = 0; s < DSTATE; ++s) { a[s] = A[(size_t)d * DSTATE + s]; h[s] = 0.f; }
  float sdt = 0.f;
  int t0 = c * CLEN;
  for (int t = t0; t < t0 + CLEN; ++t) {
    size_t ro = (size_t)(b * SEQ + t);
    float dtv = dt[ro * DINNER + d];
    float xv = xc[ro * DINNER + d];
    sdt += dtv;
    float bx = dtv * xv;
    float4 q0 = *(const float4*)(Bm + ro * DSTATE + 0);
    float4 q1 = *(const float4*)(Bm + ro * DSTATE + 4);
    float4 q2 = *(const float4*)(Bm + ro * DSTATE + 8);
    float4 q3 = *(const float4*)(Bm + ro * DSTATE + 12);
    float bm[DSTATE] = {q0.x, q0.y, q0.z, q0.w, q1.x, q1.y, q1.z, q1.w,
                        q2.x, q2.y, q2.z, q2.w, q3.x, q3.y, q3.z, q3.w};
#pragma unroll
    for (int s = 0; s < DSTATE; ++s) {
      float av = __expf(a[s] * dtv);
      h[s] = fmaf(av, h[s], bx * bm[s]);
    }
  }
  size_t o = ((size_t)(b * NCHUNK + c) * DINNER + d) * DSTATE;
#pragma unroll
  for (int s = 0; s < DSTATE; ++s) {
    hfin[o + s] = h[s];
    P[o + s] = __expf(a[s] * sdt);
  }
}

__global__ __launch_bounds__(256) void scan_chunks_k(const float* __restrict__ hfin,
                                                     const float* __restrict__ P,
                                                     float* __restrict__ Hprev) {
  int j = blockIdx.x * 256 + threadIdx.x;
  int b = j / (DINNER * DSTATE);
  int r = j % (DINNER * DSTATE);
  float H = 0.f;
  for (int c = 0; c < NCHUNK; ++c) {
    size_t o = ((size_t)(b * NCHUNK + c) * DINNER * DSTATE) + r;
    Hprev[o] = H;
    H = fmaf(P[o], H, hfin[o]);
  }
}

__global__ __launch_bounds__(256) void scan_final_k(const float* __restrict__ dt,
                                                    const float* __restrict__ xc,
                                                    const float* __restrict__ Bm,
                                                    const float* __restrict__ Cm,
                                                    const float* __restrict__ A,
                                                    const float* __restrict__ Hprev,
                                                    const float* __restrict__ Dskip,
                                                    unsigned short* __restrict__ ysbf) {
  int d = blockIdx.x * 256 + threadIdx.x;
  int c = blockIdx.y, b = blockIdx.z;
  float a[DSTATE], h[DSTATE];
  size_t ho = ((size_t)(b * NCHUNK + c) * DINNER + d) * DSTATE;
#pragma unroll
  for (int s = 0; s < DSTATE; ++s) {
    a[s] = A[(size_t)d * DSTATE + s];
    h[s] = Hprev[ho + s];
  }
  float Dv = Dskip[d];
  int t0 = c * CLEN;
  for (int t = t0; t < t0 + CLEN; ++t) {
    size_t ro = (size_t)(b * SEQ + t);
    float dtv = dt[ro * DINNER + d];
    float xv = xc[ro * DINNER + d];
    float bx = dtv * xv;
    float4 q0 = *(const float4*)(Bm + ro * DSTATE + 0);
    float4 q1 = *(const float4*)(Bm + ro * DSTATE + 4);
    float4 q2 = *(const float4*)(Bm + ro * DSTATE + 8);
    float4 q3 = *(const float4*)(Bm + ro * DSTATE + 12);
    float bm[DSTATE] = {q0.x, q0.y, q0.z, q0.w, q1.x, q1.y, q1.z, q1.w,
                        q2.x, q2.y, q2.z, q2.w, q3.x, q3.y, q3.z, q3.w};
    float4 r0 = *(const float4*)(Cm + ro * DSTATE + 0);
    float4 r1 = *(const float4*)(Cm + ro * DSTATE + 4);
    float4 r2 = *(const float4*)(Cm + ro * DSTATE + 8);
    float4 r3 = *(const float4*)(Cm + ro * DSTATE + 12);
    float cm[DSTATE] = {r0.x, r0.y, r0.z, r0.w, r1.x, r1.y, r1.z, r1.w,
                        r2.x, r2.y, r2.z, r2.w, r3.x, r3.y, r3.z, r3.w};
    float y = Dv * xv;
#pragma unroll
    for (int s = 0; s < DSTATE; ++s) {
      float av = __expf(a[s] * dtv);
      h[s] = fmaf(av, h[s], bx * bm[s]);
      y = fmaf(h[s], cm[s], y);
    }
    ysbf[ro * DINNER + d] = f2bf(y);
  }
}

extern "C" void kernel_launch(void* const* d_in, const int* in_sizes, int n_in,
                              void* d_out, int out_size, void* d_ws, size_t ws_size,
                              hipStream_t stream) {
  (void)in_sizes; (void)n_in; (void)out_size; (void)ws_size;
  const float* x       = (const float*)d_in[0];
  const float* norm_w  = (const float*)d_in[1];
  const float* in_proj = (const float*)d_in[2];
  const float* conv_w  = (const float*)d_in[3];
  const float* dt_w    = (const float*)d_in[4];
  const float* dt_b    = (const float*)d_in[5];
  const float* A_log   = (const float*)d_in[6];
  const float* B_w     = (const float*)d_in[7];
  const float* C_w     = (const float*)d_in[8];
  const float* D_skip  = (const float*)d_in[9];
  const float* out_w   = (const float*)d_in[10];
  float* out = (float*)d_out;
  float* ws = (float*)d_ws;

  // Workspace (f32 units), lifetime-aliased:
  float* Aneg = ws;                  // 32768
  float* Bm   = ws + 32768;
  float* Cm   = ws + 65536;
  float* RA   = ws + 98304;          // 2.1M f32: in_wT -> W2t(1.06M) -> Hprev(1.05M)
  float* RB   = RA + 2097152;        // 1.05M f32: xn_bf -> out_wT
  float* RC   = RB + 1048576;        // 8.39M f32: xg -> dtb(4.19M)+hfin(2.1M)+P(2.1M)
  float* RD   = RC + 8388608;        // 4.19M f32: xc
  float* RE   = RD + 4194304;        // 2.1M f32: xc_bf -> ys_bf
  unsigned short* in_wT  = (unsigned short*)RA;
  unsigned short* W2t    = (unsigned short*)RA;
  float*          Hprev  = RA;
  unsigned short* xn_bf  = (unsigned short*)RB;
  unsigned short* out_wT = (unsigned short*)RB;
  float* xg   = RC;
  float* dtb  = RC;
  float* hfin = RC + 4194304;
  float* Pbuf = RC + 6291456;
  float* xc   = RD;
  unsigned short* xc_bf = (unsigned short*)RE;
  unsigned short* ys_bf = (unsigned short*)RE;

  init_aneg_k<<<dim3(DINNER * DSTATE / 256), dim3(256), 0, stream>>>(A_log, Aneg);
  transpose_cvt_k<<<dim3(2 * DINNER / 32, DMODEL / 32), dim3(32, 8), 0, stream>>>(
      in_proj, in_wT, DMODEL, 2 * DINNER);
  rmsnorm_k<<<dim3(NTOK), dim3(256), 0, stream>>>(x, norm_w, xn_bf);
  gemm_bf16_t<128, 128, 0><<<dim3(2 * DINNER / 128, NTOK / 128), dim3(256), 0, stream>>>(
      xn_bf, in_wT, xg, NTOK, 2 * DINNER, DMODEL, 2 * DINNER, nullptr, nullptr, nullptr);
  siluconv_k<<<dim3(NTOK * (DINNER / 4) / 8 / 256), dim3(256), 0, stream>>>(
      xg, conv_w, xc, xc_bf);
  build_w2t_k<<<dim3(DINNER / 32, NEXT / 32), dim3(32, 8), 0, stream>>>(
      dt_w, B_w, C_w, W2t);
  gemm_bf16_t<128, 64, 2><<<dim3(NEXT / 64, NTOK / 128), dim3(256), 0, stream>>>(
      xc_bf, W2t, dtb, NTOK, NEXT, DINNER, DINNER, dt_b, Bm, Cm);
  scan_local_k<<<dim3(DINNER / 256, NCHUNK, BATCH), dim3(256), 0, stream>>>(
      dtb, xc, Bm, Aneg, hfin, Pbuf);
  scan_chunks_k<<<dim3(BATCH * DINNER * DSTATE / 256), dim3(256), 0, stream>>>(
      hfin, Pbuf, Hprev);
  scan_final_k<<<dim3(DINNER / 256, NCHUNK, BATCH), dim3(256), 0, stream>>>(
      dtb, xc, Bm, Cm, Aneg, Hprev, D_skip, ys_bf);
  transpose_cvt_k<<<dim3(DMODEL / 32, DINNER / 32), dim3(32, 8), 0, stream>>>(
      out_w, out_wT, DINNER, DMODEL);
  gemm_bf16_t<64, 64, 0><<<dim3(DMODEL / 64, NTOK / 64), dim3(256), 0, stream>>>(
      ys_bf, out_wT, out, NTOK, DMODEL, DINNER, DMODEL, nullptr, nullptr, nullptr);
}

// Round 6
// 184.781 us; speedup vs baseline: 1.3409x; 1.3409x over previous
//
#include <hip/hip_runtime.h>
#include <cmath>

// SSM forward, round 6: fragment-TILED global layout for all GEMM operands
// (1KB contiguous per 16x32 subtile in MFMA lane order) -> perfectly coalesced
// global_load_lds staging AND conflict-free linear LDS reads. BK=64.
// Scans read bf16 xc (f32 xc eliminated).

#define SEQ    1024
#define BATCH  2
#define DMODEL 1024
#define DINNER 2048
#define DSTATE 16
#define NTOK   (BATCH * SEQ)
#define NCHUNK 32
#define CLEN   32
#define NEXT   2112  // DINNER + 16 + 16 + 32 pad (64-multiple)

typedef __attribute__((ext_vector_type(8))) short short8;
typedef __attribute__((ext_vector_type(4))) float f32x4;

__device__ __forceinline__ unsigned short f2bf(float f) {
  unsigned int u = __float_as_uint(f);
  unsigned int r = (u + 0x7fffu + ((u >> 16) & 1u)) >> 16;
  return (unsigned short)r;
}
__device__ __forceinline__ float bf2f(unsigned short v) {
  return __uint_as_float((unsigned int)v << 16);
}
__device__ __forceinline__ float softplus_f(float x) {
  return (x > 20.f) ? x : log1pf(__expf(x));
}
__device__ __forceinline__ void gload_lds16(const void* g, void* l) {
  __builtin_amdgcn_global_load_lds(
      (const __attribute__((address_space(1))) unsigned int*)g,
      (__attribute__((address_space(3))) unsigned int*)l, 16, 0, 0);
}

// Fragment-tiled layout: element (row, k) of a [R][K] bf16 matrix lives at
// short index: block(row>>4, k>>5)*512 + lane(row&15, (k>>3)&3)*8 + (k&7),
// where lane l of the staging wave holds row l&15, k-chunk l>>4.
__device__ __forceinline__ size_t tiled_off(int row, int k, int kblks) {
  return ((size_t)(row >> 4) * kblks + (k >> 5)) * 512
       + ((size_t)((row & 15) + (((k >> 3) & 3) << 4)) << 3) + (k & 7);
}

__global__ __launch_bounds__(256) void init_aneg_k(const float* __restrict__ A_log,
                                                   float* __restrict__ Aneg) {
  int i = blockIdx.x * 256 + threadIdx.x;
  Aneg[i] = -__expf(A_log[i]);
}

// W[K][N] f32 -> tiled bf16 (rows = n, reduction = k).
__global__ void transpose_cvt_k(const float* __restrict__ W, unsigned short* __restrict__ Wt,
                                int K, int N) {
  __shared__ float tile[32][33];
  int k0 = blockIdx.y * 32, n0 = blockIdx.x * 32;
  int tx = threadIdx.x, ty = threadIdx.y;  // 32 x 8
  int kblks = K >> 5;
#pragma unroll
  for (int i = 0; i < 32; i += 8)
    tile[ty + i][tx] = W[(size_t)(k0 + ty + i) * N + n0 + tx];
  __syncthreads();
#pragma unroll
  for (int i = 0; i < 32; i += 8)
    Wt[tiled_off(n0 + ty + i, k0 + tx, kblks)] = f2bf(tile[tx][ty + i]);
}

// Combined dt|B|C weight, tiled: rows [0,2048)=dt_w^T, [2048,2064)=B_w^T,
// [2064,2080)=C_w^T, [2080,2112)=0. kblks = 64.
__global__ void build_w2t_k(const float* __restrict__ dt_w, const float* __restrict__ B_w,
                            const float* __restrict__ C_w, unsigned short* __restrict__ Wt) {
  __shared__ float tile[32][33];
  int k0 = blockIdx.x * 32, n0 = blockIdx.y * 32;
  int tx = threadIdx.x, ty = threadIdx.y;  // 32 x 8
  if (n0 < DINNER) {
#pragma unroll
    for (int i = 0; i < 32; i += 8)
      tile[ty + i][tx] = dt_w[(size_t)(k0 + ty + i) * DINNER + n0 + tx];
    __syncthreads();
#pragma unroll
    for (int i = 0; i < 32; i += 8)
      Wt[tiled_off(n0 + ty + i, k0 + tx, 64)] = f2bf(tile[tx][ty + i]);
  } else {
#pragma unroll
    for (int i = 0; i < 32; i += 8) {
      int n = n0 + ty + i;
      float v = 0.f;
      if (n < DINNER + 16) v = B_w[(size_t)(k0 + tx) * DSTATE + (n - DINNER)];
      else if (n < DINNER + 32) v = C_w[(size_t)(k0 + tx) * DSTATE + (n - DINNER - 16)];
      Wt[tiled_off(n, k0 + tx, 64)] = f2bf(v);
    }
  }
}

__global__ __launch_bounds__(256) void rmsnorm_k(const float* __restrict__ x,
                                                 const float* __restrict__ w,
                                                 unsigned short* __restrict__ xnbf) {
  int row = blockIdx.x, tid = threadIdx.x;
  const float4 v = *(const float4*)(x + (size_t)row * DMODEL + tid * 4);
  float ss = v.x * v.x + v.y * v.y + v.z * v.z + v.w * v.w;
#pragma unroll
  for (int off = 32; off > 0; off >>= 1) ss += __shfl_down(ss, off);
  __shared__ float red[4];
  if ((tid & 63) == 0) red[tid >> 6] = ss;
  __syncthreads();
  float tot = red[0] + red[1] + red[2] + red[3];
  float scale = rsqrtf(tot * (1.0f / DMODEL) + 1e-6f);
  const float4 wv = *(const float4*)(w + tid * 4);
  ushort4 o;
  o.x = f2bf(v.x * scale * wv.x);
  o.y = f2bf(v.y * scale * wv.y);
  o.z = f2bf(v.z * scale * wv.z);
  o.w = f2bf(v.w * scale * wv.w);
  *(ushort4*)(xnbf + tiled_off(row, tid * 4, DMODEL / 32)) = o;
}

// C = A @ Bt^T, both operands fragment-TILED bf16, f32 out. BK=64, 4 waves (2x2),
// double-buffered LDS, 1 barrier/K-step, XCD swizzle. Staging: each
// global_load_lds reads one 1KB subtile fully contiguous (lane l -> bytes l*16).
// MODE 0: plain C. MODE 2: dt|B|C combined epilogue.
template <int BM, int BN, int MODE>
__global__ __launch_bounds__(256) void gemm_bf16_t(const unsigned short* __restrict__ At,
                                                   const unsigned short* __restrict__ Btt,
                                                   float* __restrict__ C,
                                                   int M, int N, int K, int ldc,
                                                   const float* __restrict__ bias,
                                                   float* __restrict__ Bm,
                                                   float* __restrict__ Cm) {
  constexpr int WTM = BM / 2, WTN = BN / 2;
  constexpr int FM = WTM / 16, FN = WTN / 16;
  constexpr int ASUB = BM / 16, BSUB = BN / 16;     // subtiles per kblk
  constexpr int ALOAD = ASUB * 2, BLOAD = BSUB * 2; // per K-step (2 kblks)
  __shared__ __align__(16) unsigned short Abuf[2][BM * 64];
  __shared__ __align__(16) unsigned short Bbuf[2][BN * 64];
  const int tid = threadIdx.x;
  const int wave = tid >> 6, lane = tid & 63;

  const int gx = gridDim.x;
  int lin = blockIdx.y * gx + blockIdx.x;
  int nwg = gx * gridDim.y;
  int swz = (lin & 7) * (nwg >> 3) + (lin >> 3);
  const int bm = (swz / gx) * BM, bn = (swz % gx) * BN;

  const int wm = wave >> 1, wn = wave & 1;
  const int kblks = K >> 5;
  const unsigned short* Ag = At + ((size_t)(bm >> 4) * kblks) * 512 + (lane << 3);
  const unsigned short* Bg = Btt + ((size_t)(bn >> 4) * kblks) * 512 + (lane << 3);

  auto stage = [&](int buf, int t) {
#pragma unroll
    for (int i = wave; i < ALOAD; i += 4) {
      int s = i >> 1, kk = i & 1;
      gload_lds16(Ag + ((size_t)s * kblks + 2 * t + kk) * 512,
                  &Abuf[buf][(kk * ASUB + s) * 512]);
    }
#pragma unroll
    for (int i = wave; i < BLOAD; i += 4) {
      int s = i >> 1, kk = i & 1;
      gload_lds16(Bg + ((size_t)s * kblks + 2 * t + kk) * 512,
                  &Bbuf[buf][(kk * BSUB + s) * 512]);
    }
  };

  f32x4 acc[FM][FN] = {};
  const int nt = K / 64;
  stage(0, 0);
  __syncthreads();
  int cur = 0;
  for (int t = 0; t < nt; ++t) {
    if (t + 1 < nt) stage(cur ^ 1, t + 1);
#pragma unroll
    for (int kk = 0; kk < 2; ++kk) {
      short8 af[FM], bfr[FN];
#pragma unroll
      for (int m = 0; m < FM; ++m)
        af[m] = *(const short8*)&Abuf[cur][(kk * ASUB + wm * FM + m) * 512 + (lane << 3)];
#pragma unroll
      for (int n = 0; n < FN; ++n)
        bfr[n] = *(const short8*)&Bbuf[cur][(kk * BSUB + wn * FN + n) * 512 + (lane << 3)];
#pragma unroll
      for (int m = 0; m < FM; ++m)
#pragma unroll
        for (int n = 0; n < FN; ++n)
          acc[m][n] = __builtin_amdgcn_mfma_f32_16x16x32_bf16(af[m], bfr[n], acc[m][n], 0, 0, 0);
    }
    __syncthreads();  // drains stage(t+1) vmem + guards dbuf WAR
    cur ^= 1;
  }

  const int rbase = bm + wm * WTM + (lane >> 4) * 4;
  const int cbase = bn + wn * WTN + (lane & 15);
#pragma unroll
  for (int m = 0; m < FM; ++m)
#pragma unroll
    for (int n = 0; n < FN; ++n) {
      int col = cbase + n * 16;
#pragma unroll
      for (int r = 0; r < 4; ++r) {
        int row = rbase + m * 16 + r;
        float v = acc[m][n][r];
        if (MODE == 0) {
          C[(size_t)row * ldc + col] = v;
        } else {  // MODE 2 (dt | B | C combined)
          if (col < DINNER)
            C[(size_t)row * DINNER + col] = softplus_f(v + bias[col]);
          else if (col < DINNER + 16)
            Bm[(size_t)row * DSTATE + (col - DINNER)] = v;
          else if (col < DINNER + 32)
            Cm[(size_t)row * DSTATE + (col - DINNER - 16)] = v;
        }
      }
    }
}

// Fused: x_inner = a * silu(g), causal depthwise conv width 4; writes TILED bf16 only.
__global__ __launch_bounds__(256) void siluconv_k(const float* __restrict__ xg,
                                                  const float* __restrict__ w,
                                                  unsigned short* __restrict__ xcbf) {
  int idx = blockIdx.x * 256 + threadIdx.x;
  int d4 = (idx & 511) << 2;
  int tc = (idx >> 9) & 127;
  int b = idx >> 16;
  float4 w0 = *(const float4*)(w + (d4 + 0) * 4);
  float4 w1 = *(const float4*)(w + (d4 + 1) * 4);
  float4 w2 = *(const float4*)(w + (d4 + 2) * 4);
  float4 w3 = *(const float4*)(w + (d4 + 3) * 4);
  const float wj0[4] = {w0.x, w0.y, w0.z, w0.w};
  const float wj1[4] = {w1.x, w1.y, w1.z, w1.w};
  const float wj2[4] = {w2.x, w2.y, w2.z, w2.w};
  const float wj3[4] = {w3.x, w3.y, w3.z, w3.w};
  const float* pa = xg + (size_t)b * SEQ * (2 * DINNER) + d4;
  const float* pg = pa + DINNER;
  int t0 = tc * 8;
  float4 sA = {0.f, 0.f, 0.f, 0.f}, sB = sA, sC = sA;
  auto gated = [&](int t) {
    float4 a = *(const float4*)(pa + (size_t)t * (2 * DINNER));
    float4 g = *(const float4*)(pg + (size_t)t * (2 * DINNER));
    float4 r;
    r.x = a.x * (g.x / (1.f + __expf(-g.x)));
    r.y = a.y * (g.y / (1.f + __expf(-g.y)));
    r.z = a.z * (g.z / (1.f + __expf(-g.z)));
    r.w = a.w * (g.w / (1.f + __expf(-g.w)));
    return r;
  };
  if (t0 > 0) {
    sA = gated(t0 - 3);
    sB = gated(t0 - 2);
    sC = gated(t0 - 1);
  }
#pragma unroll
  for (int j = 0; j < 8; ++j) {
    int t = t0 + j;
    float4 sD = gated(t);
    float4 o;
    o.x = sA.x * wj0[0] + sB.x * wj0[1] + sC.x * wj0[2] + sD.x * wj0[3];
    o.y = sA.y * wj1[0] + sB.y * wj1[1] + sC.y * wj1[2] + sD.y * wj1[3];
    o.z = sA.z * wj2[0] + sB.z * wj2[1] + sC.z * wj2[2] + sD.z * wj2[3];
    o.w = sA.w * wj3[0] + sB.w * wj3[1] + sC.w * wj3[2] + sD.w * wj3[3];
    ushort4 ob = {f2bf(o.x), f2bf(o.y), f2bf(o.z), f2bf(o.w)};
    *(ushort4*)(xcbf + tiled_off(b * SEQ + t, d4, 64)) = ob;
    sA = sB; sB = sC; sC = sD;
  }
}

__global__ __launch_bounds__(256) void scan_local_k(const float* __restrict__ dt,
                                                    const unsigned short* __restrict__ xcbf,
                                                    const float* __restrict__ Bm,
                                                    const float* __restrict__ A,
                                                    float* __restrict__ hfin,
                                                    float* __restrict__ P) {
  int d = blockIdx.x * 256 + threadIdx.x;
  int c = blockIdx.y, b = blockIdx.z;
  float a[DSTATE], h[DSTATE];
#pragma unroll
  for (int s = 0; s < DSTATE; ++s) { a[s] = A[(size_t)d * DSTATE + s]; h[s] = 0.f; }
  float sdt = 0.f;
  int t0 = c * CLEN;
  for (int t = t0; t < t0 + CLEN; ++t) {
    size_t ro = (size_t)(b * SEQ + t);
    float dtv = dt[ro * DINNER + d];
    float xv = bf2f(xcbf[tiled_off((int)ro, d, 64)]);
    sdt += dtv;
    float bx = dtv * xv;
    float4 q0 = *(const float4*)(Bm + ro * DSTATE + 0);
    float4 q1 = *(const float4*)(Bm + ro * DSTATE + 4);
    float4 q2 = *(const float4*)(Bm + ro * DSTATE + 8);
    float4 q3 = *(const float4*)(Bm + ro * DSTATE + 12);
    float bm[DSTATE] = {q0.x, q0.y, q0.z, q0.w, q1.x, q1.y, q1.z, q1.w,
                        q2.x, q2.y, q2.z, q2.w, q3.x, q3.y, q3.z, q3.w};
#pragma unroll
    for (int s = 0; s < DSTATE; ++s) {
      float av = __expf(a[s] * dtv);
      h[s] = fmaf(av, h[s], bx * bm[s]);
    }
  }
  size_t o = ((size_t)(b * NCHUNK + c) * DINNER + d) * DSTATE;
#pragma unroll
  for (int s = 0; s < DSTATE; ++s) {
    hfin[o + s] = h[s];
    P[o + s] = __expf(a[s] * sdt);
  }
}

// In-place: hp holds hfin on entry, Hprev (state entering chunk c) on exit.
__global__ __launch_bounds__(256) void scan_chunks_k(float* hp, const float* __restrict__ P) {
  int j = blockIdx.x * 256 + threadIdx.x;
  int b = j / (DINNER * DSTATE);
  int r = j % (DINNER * DSTATE);
  float H = 0.f;
  for (int c = 0; c < NCHUNK; ++c) {
    size_t o = ((size_t)(b * NCHUNK + c) * DINNER * DSTATE) + r;
    float hf = hp[o];
    float pv = P[o];
    hp[o] = H;
    H = fmaf(pv, H, hf);
  }
}

__global__ __launch_bounds__(256) void scan_final_k(const float* __restrict__ dt,
                                                    const unsigned short* __restrict__ xcbf,
                                                    const float* __restrict__ Bm,
                                                    const float* __restrict__ Cm,
                                                    const float* __restrict__ A,
                                                    const float* __restrict__ Hprev,
                                                    const float* __restrict__ Dskip,
                                                    unsigned short* __restrict__ ysbf) {
  int d = blockIdx.x * 256 + threadIdx.x;
  int c = blockIdx.y, b = blockIdx.z;
  float a[DSTATE], h[DSTATE];
  size_t ho = ((size_t)(b * NCHUNK + c) * DINNER + d) * DSTATE;
#pragma unroll
  for (int s = 0; s < DSTATE; ++s) {
    a[s] = A[(size_t)d * DSTATE + s];
    h[s] = Hprev[ho + s];
  }
  float Dv = Dskip[d];
  int t0 = c * CLEN;
  for (int t = t0; t < t0 + CLEN; ++t) {
    size_t ro = (size_t)(b * SEQ + t);
    float dtv = dt[ro * DINNER + d];
    float xv = bf2f(xcbf[tiled_off((int)ro, d, 64)]);
    float bx = dtv * xv;
    float4 q0 = *(const float4*)(Bm + ro * DSTATE + 0);
    float4 q1 = *(const float4*)(Bm + ro * DSTATE + 4);
    float4 q2 = *(const float4*)(Bm + ro * DSTATE + 8);
    float4 q3 = *(const float4*)(Bm + ro * DSTATE + 12);
    float bm[DSTATE] = {q0.x, q0.y, q0.z, q0.w, q1.x, q1.y, q1.z, q1.w,
                        q2.x, q2.y, q2.z, q2.w, q3.x, q3.y, q3.z, q3.w};
    float4 r0 = *(const float4*)(Cm + ro * DSTATE + 0);
    float4 r1 = *(const float4*)(Cm + ro * DSTATE + 4);
    float4 r2 = *(const float4*)(Cm + ro * DSTATE + 8);
    float4 r3 = *(const float4*)(Cm + ro * DSTATE + 12);
    float cm[DSTATE] = {r0.x, r0.y, r0.z, r0.w, r1.x, r1.y, r1.z, r1.w,
                        r2.x, r2.y, r2.z, r2.w, r3.x, r3.y, r3.z, r3.w};
    float y = Dv * xv;
#pragma unroll
    for (int s = 0; s < DSTATE; ++s) {
      float av = __expf(a[s] * dtv);
      h[s] = fmaf(av, h[s], bx * bm[s]);
      y = fmaf(h[s], cm[s], y);
    }
    ysbf[tiled_off((int)ro, d, 64)] = f2bf(y);
  }
}

extern "C" void kernel_launch(void* const* d_in, const int* in_sizes, int n_in,
                              void* d_out, int out_size, void* d_ws, size_t ws_size,
                              hipStream_t stream) {
  (void)in_sizes; (void)n_in; (void)out_size; (void)ws_size;
  const float* x       = (const float*)d_in[0];
  const float* norm_w  = (const float*)d_in[1];
  const float* in_proj = (const float*)d_in[2];
  const float* conv_w  = (const float*)d_in[3];
  const float* dt_w    = (const float*)d_in[4];
  const float* dt_b    = (const float*)d_in[5];
  const float* A_log   = (const float*)d_in[6];
  const float* B_w     = (const float*)d_in[7];
  const float* C_w     = (const float*)d_in[8];
  const float* D_skip  = (const float*)d_in[9];
  const float* out_w   = (const float*)d_in[10];
  float* out = (float*)d_out;
  float* ws = (float*)d_ws;

  // Workspace (f32 units), total ~63.6 MB, lifetime-aliased:
  float* Aneg = ws;                  // 32768
  float* Bm   = ws + 32768;
  float* Cm   = ws + 65536;
  float* b0   = ws + 98304;
  float* xg   = b0;                  // 8M f32 (steps 4-5)
  float* dtb  = b0;                  // 4M (7-10, xg dead)
  float* hfin = b0 + 4194304;        // 2M (8-10; becomes Hprev in-place)
  float* Pbuf = b0 + 6291456;        // 2M (8-9)
  unsigned short* xc_bf = (unsigned short*)(b0 + 8388608);   // 4M shorts (5-10)
  unsigned short* ys_bf = (unsigned short*)(b0 + 10485760);  // 4M shorts (10-12)
  float* Rw   = b0 + 12582912;       // 2162688 f32: in_wT(2-4) -> W2t(6-7) -> out_wT(11-12)
  unsigned short* in_wT  = (unsigned short*)Rw;
  unsigned short* W2t    = (unsigned short*)Rw;
  unsigned short* out_wT = (unsigned short*)Rw;
  unsigned short* xn_bf  = (unsigned short*)(b0 + 14745600); // 2M shorts (3-4)

  init_aneg_k<<<dim3(DINNER * DSTATE / 256), dim3(256), 0, stream>>>(A_log, Aneg);
  transpose_cvt_k<<<dim3(2 * DINNER / 32, DMODEL / 32), dim3(32, 8), 0, stream>>>(
      in_proj, in_wT, DMODEL, 2 * DINNER);
  rmsnorm_k<<<dim3(NTOK), dim3(256), 0, stream>>>(x, norm_w, xn_bf);
  gemm_bf16_t<128, 128, 0><<<dim3(2 * DINNER / 128, NTOK / 128), dim3(256), 0, stream>>>(
      xn_bf, in_wT, xg, NTOK, 2 * DINNER, DMODEL, 2 * DINNER, nullptr, nullptr, nullptr);
  siluconv_k<<<dim3(NTOK * (DINNER / 4) / 8 / 256), dim3(256), 0, stream>>>(
      xg, conv_w, xc_bf);
  build_w2t_k<<<dim3(DINNER / 32, NEXT / 32), dim3(32, 8), 0, stream>>>(
      dt_w, B_w, C_w, W2t);
  gemm_bf16_t<128, 64, 2><<<dim3(NEXT / 64, NTOK / 128), dim3(256), 0, stream>>>(
      xc_bf, W2t, dtb, NTOK, NEXT, DINNER, DINNER, dt_b, Bm, Cm);
  scan_local_k<<<dim3(DINNER / 256, NCHUNK, BATCH), dim3(256), 0, stream>>>(
      dtb, xc_bf, Bm, Aneg, hfin, Pbuf);
  scan_chunks_k<<<dim3(BATCH * DINNER * DSTATE / 256), dim3(256), 0, stream>>>(
      hfin, Pbuf);
  scan_final_k<<<dim3(DINNER / 256, NCHUNK, BATCH), dim3(256), 0, stream>>>(
      dtb, xc_bf, Bm, Cm, Aneg, hfin, D_skip, ys_bf);
  transpose_cvt_k<<<dim3(DMODEL / 32, DINNER / 32), dim3(32, 8), 0, stream>>>(
      out_w, out_wT, DINNER, DMODEL);
  gemm_bf16_t<64, 64, 0><<<dim3(DMODEL / 64, NTOK / 64), dim3(256), 0, stream>>>(
      ys_bf, out_wT, out, NTOK, DMODEL, DINNER, DMODEL, nullptr, nullptr, nullptr);
}

// Round 7
// 178.724 us; speedup vs baseline: 1.3863x; 1.0339x over previous
//
#include <hip/hip_runtime.h>
#include <cmath>

// SSM forward, round 7: counted-vmcnt 2-deep pipelined GEMM (no vmcnt(0) drain in
// the K-loop), fragment-tiled operands, raw s_barrier, BK=64.

#define SEQ    1024
#define BATCH  2
#define DMODEL 1024
#define DINNER 2048
#define DSTATE 16
#define NTOK   (BATCH * SEQ)
#define NCHUNK 32
#define CLEN   32
#define NEXT   2112  // DINNER + 16 + 16 + 32 pad (64-multiple)

typedef __attribute__((ext_vector_type(8))) short short8;
typedef __attribute__((ext_vector_type(4))) float f32x4;

__device__ __forceinline__ unsigned short f2bf(float f) {
  unsigned int u = __float_as_uint(f);
  unsigned int r = (u + 0x7fffu + ((u >> 16) & 1u)) >> 16;
  return (unsigned short)r;
}
__device__ __forceinline__ float bf2f(unsigned short v) {
  return __uint_as_float((unsigned int)v << 16);
}
__device__ __forceinline__ float softplus_f(float x) {
  return (x > 20.f) ? x : log1pf(__expf(x));
}
__device__ __forceinline__ void gload_lds16(const void* g, void* l) {
  __builtin_amdgcn_global_load_lds(
      (const __attribute__((address_space(1))) unsigned int*)g,
      (__attribute__((address_space(3))) unsigned int*)l, 16, 0, 0);
}

template <int N>
__device__ __forceinline__ void wait_vmcnt() {
  if constexpr (N >= 8)      asm volatile("s_waitcnt vmcnt(8)" ::: "memory");
  else if constexpr (N == 6) asm volatile("s_waitcnt vmcnt(6)" ::: "memory");
  else if constexpr (N == 4) asm volatile("s_waitcnt vmcnt(4)" ::: "memory");
  else                       asm volatile("s_waitcnt vmcnt(0)" ::: "memory");
}

// Fragment-tiled layout: element (row, k) of a [R][K] bf16 matrix lives at
// short index: block(row>>4, k>>5)*512 + lane(row&15, (k>>3)&3)*8 + (k&7).
__device__ __forceinline__ size_t tiled_off(int row, int k, int kblks) {
  return ((size_t)(row >> 4) * kblks + (k >> 5)) * 512
       + ((size_t)((row & 15) + (((k >> 3) & 3) << 4)) << 3) + (k & 7);
}

__global__ __launch_bounds__(256) void init_aneg_k(const float* __restrict__ A_log,
                                                   float* __restrict__ Aneg) {
  int i = blockIdx.x * 256 + threadIdx.x;
  Aneg[i] = -__expf(A_log[i]);
}

// W[K][N] f32 -> tiled bf16 (rows = n, reduction = k).
__global__ void transpose_cvt_k(const float* __restrict__ W, unsigned short* __restrict__ Wt,
                                int K, int N) {
  __shared__ float tile[32][33];
  int k0 = blockIdx.y * 32, n0 = blockIdx.x * 32;
  int tx = threadIdx.x, ty = threadIdx.y;  // 32 x 8
  int kblks = K >> 5;
#pragma unroll
  for (int i = 0; i < 32; i += 8)
    tile[ty + i][tx] = W[(size_t)(k0 + ty + i) * N + n0 + tx];
  __syncthreads();
#pragma unroll
  for (int i = 0; i < 32; i += 8)
    Wt[tiled_off(n0 + ty + i, k0 + tx, kblks)] = f2bf(tile[tx][ty + i]);
}

// Combined dt|B|C weight, tiled: rows [0,2048)=dt_w^T, [2048,2064)=B_w^T,
// [2064,2080)=C_w^T, [2080,2112)=0. kblks = 64.
__global__ void build_w2t_k(const float* __restrict__ dt_w, const float* __restrict__ B_w,
                            const float* __restrict__ C_w, unsigned short* __restrict__ Wt) {
  __shared__ float tile[32][33];
  int k0 = blockIdx.x * 32, n0 = blockIdx.y * 32;
  int tx = threadIdx.x, ty = threadIdx.y;  // 32 x 8
  if (n0 < DINNER) {
#pragma unroll
    for (int i = 0; i < 32; i += 8)
      tile[ty + i][tx] = dt_w[(size_t)(k0 + ty + i) * DINNER + n0 + tx];
    __syncthreads();
#pragma unroll
    for (int i = 0; i < 32; i += 8)
      Wt[tiled_off(n0 + ty + i, k0 + tx, 64)] = f2bf(tile[tx][ty + i]);
  } else {
#pragma unroll
    for (int i = 0; i < 32; i += 8) {
      int n = n0 + ty + i;
      float v = 0.f;
      if (n < DINNER + 16) v = B_w[(size_t)(k0 + tx) * DSTATE + (n - DINNER)];
      else if (n < DINNER + 32) v = C_w[(size_t)(k0 + tx) * DSTATE + (n - DINNER - 16)];
      Wt[tiled_off(n, k0 + tx, 64)] = f2bf(v);
    }
  }
}

__global__ __launch_bounds__(256) void rmsnorm_k(const float* __restrict__ x,
                                                 const float* __restrict__ w,
                                                 unsigned short* __restrict__ xnbf) {
  int row = blockIdx.x, tid = threadIdx.x;
  const float4 v = *(const float4*)(x + (size_t)row * DMODEL + tid * 4);
  float ss = v.x * v.x + v.y * v.y + v.z * v.z + v.w * v.w;
#pragma unroll
  for (int off = 32; off > 0; off >>= 1) ss += __shfl_down(ss, off);
  __shared__ float red[4];
  if ((tid & 63) == 0) red[tid >> 6] = ss;
  __syncthreads();
  float tot = red[0] + red[1] + red[2] + red[3];
  float scale = rsqrtf(tot * (1.0f / DMODEL) + 1e-6f);
  const float4 wv = *(const float4*)(w + tid * 4);
  ushort4 o;
  o.x = f2bf(v.x * scale * wv.x);
  o.y = f2bf(v.y * scale * wv.y);
  o.z = f2bf(v.z * scale * wv.z);
  o.w = f2bf(v.w * scale * wv.w);
  *(ushort4*)(xnbf + tiled_off(row, tid * 4, DMODEL / 32)) = o;
}

// C = A @ Bt^T, operands fragment-TILED bf16, f32 out. BK=64, 4 waves (2x2).
// 2-deep counted-vmcnt pipeline: stage(t), stage(t+1) in prologue; iter t waits
// vmcnt(LPW) (t landed, t+1 in flight), barrier, ds_read->regs, lgkmcnt(0)+
// sched_barrier, barrier, stage(t+2), MFMA. No vmcnt(0) drain in the loop.
// MODE 0: plain C. MODE 2: dt|B|C combined epilogue.
template <int BM, int BN, int MODE>
__global__ __launch_bounds__(256) void gemm_bf16_t(const unsigned short* __restrict__ At,
                                                   const unsigned short* __restrict__ Btt,
                                                   float* __restrict__ C,
                                                   int M, int N, int K, int ldc,
                                                   const float* __restrict__ bias,
                                                   float* __restrict__ Bm,
                                                   float* __restrict__ Cm) {
  constexpr int WTM = BM / 2, WTN = BN / 2;
  constexpr int FM = WTM / 16, FN = WTN / 16;
  constexpr int ASUB = BM / 16, BSUB = BN / 16;     // subtiles per kblk
  constexpr int ALOAD = ASUB * 2, BLOAD = BSUB * 2; // per K-step (2 kblks)
  constexpr int LPW = (BM + BN) / 32;               // loads per wave per stage
  __shared__ __align__(16) unsigned short Abuf[2][BM * 64];
  __shared__ __align__(16) unsigned short Bbuf[2][BN * 64];
  const int tid = threadIdx.x;
  const int wave = tid >> 6, lane = tid & 63;

  const int gx = gridDim.x;
  int lin = blockIdx.y * gx + blockIdx.x;
  int nwg = gx * gridDim.y;
  int swz = (lin & 7) * (nwg >> 3) + (lin >> 3);
  const int bm = (swz / gx) * BM, bn = (swz % gx) * BN;

  const int wm = wave >> 1, wn = wave & 1;
  const int kblks = K >> 5;
  const unsigned short* Ag = At + ((size_t)(bm >> 4) * kblks) * 512 + (lane << 3);
  const unsigned short* Bg = Btt + ((size_t)(bn >> 4) * kblks) * 512 + (lane << 3);

  auto stage = [&](int buf, int t) {
#pragma unroll
    for (int i = wave; i < ALOAD; i += 4) {
      int s = i >> 1, kk = i & 1;
      gload_lds16(Ag + ((size_t)s * kblks + 2 * t + kk) * 512,
                  &Abuf[buf][(kk * ASUB + s) * 512]);
    }
#pragma unroll
    for (int i = wave; i < BLOAD; i += 4) {
      int s = i >> 1, kk = i & 1;
      gload_lds16(Bg + ((size_t)s * kblks + 2 * t + kk) * 512,
                  &Bbuf[buf][(kk * BSUB + s) * 512]);
    }
  };

  f32x4 acc[FM][FN] = {};
  const int nt = K / 64;
  stage(0, 0);
  stage(1, 1);
  for (int t = 0; t < nt; ++t) {
    const int cur = t & 1;
    if (t + 1 < nt) wait_vmcnt<LPW>();  // tile-t loads landed; t+1 stays in flight
    else            wait_vmcnt<0>();
    __builtin_amdgcn_s_barrier();       // whole tile t visible in LDS
    short8 af[2][FM], bfr[2][FN];
#pragma unroll
    for (int kk = 0; kk < 2; ++kk) {
#pragma unroll
      for (int m = 0; m < FM; ++m)
        af[kk][m] = *(const short8*)&Abuf[cur][(kk * ASUB + wm * FM + m) * 512 + (lane << 3)];
#pragma unroll
      for (int n = 0; n < FN; ++n)
        bfr[kk][n] = *(const short8*)&Bbuf[cur][(kk * BSUB + wn * FN + n) * 512 + (lane << 3)];
    }
    asm volatile("s_waitcnt lgkmcnt(0)" ::: "memory");
    __builtin_amdgcn_sched_barrier(0);
    __builtin_amdgcn_s_barrier();       // all waves done reading buf[cur]
    if (t + 2 < nt) stage(cur, t + 2);  // overwrite is now safe
#pragma unroll
    for (int kk = 0; kk < 2; ++kk)
#pragma unroll
      for (int m = 0; m < FM; ++m)
#pragma unroll
        for (int n = 0; n < FN; ++n)
          acc[m][n] = __builtin_amdgcn_mfma_f32_16x16x32_bf16(af[kk][m], bfr[kk][n],
                                                              acc[m][n], 0, 0, 0);
  }

  const int rbase = bm + wm * WTM + (lane >> 4) * 4;
  const int cbase = bn + wn * WTN + (lane & 15);
#pragma unroll
  for (int m = 0; m < FM; ++m)
#pragma unroll
    for (int n = 0; n < FN; ++n) {
      int col = cbase + n * 16;
#pragma unroll
      for (int r = 0; r < 4; ++r) {
        int row = rbase + m * 16 + r;
        float v = acc[m][n][r];
        if (MODE == 0) {
          C[(size_t)row * ldc + col] = v;
        } else {  // MODE 2 (dt | B | C combined)
          if (col < DINNER)
            C[(size_t)row * DINNER + col] = softplus_f(v + bias[col]);
          else if (col < DINNER + 16)
            Bm[(size_t)row * DSTATE + (col - DINNER)] = v;
          else if (col < DINNER + 32)
            Cm[(size_t)row * DSTATE + (col - DINNER - 16)] = v;
        }
      }
    }
}

// Fused: x_inner = a * silu(g), causal depthwise conv width 4; writes TILED bf16 only.
__global__ __launch_bounds__(256) void siluconv_k(const float* __restrict__ xg,
                                                  const float* __restrict__ w,
                                                  unsigned short* __restrict__ xcbf) {
  int idx = blockIdx.x * 256 + threadIdx.x;
  int d4 = (idx & 511) << 2;
  int tc = (idx >> 9) & 127;
  int b = idx >> 16;
  float4 w0 = *(const float4*)(w + (d4 + 0) * 4);
  float4 w1 = *(const float4*)(w + (d4 + 1) * 4);
  float4 w2 = *(const float4*)(w + (d4 + 2) * 4);
  float4 w3 = *(const float4*)(w + (d4 + 3) * 4);
  const float wj0[4] = {w0.x, w0.y, w0.z, w0.w};
  const float wj1[4] = {w1.x, w1.y, w1.z, w1.w};
  const float wj2[4] = {w2.x, w2.y, w2.z, w2.w};
  const float wj3[4] = {w3.x, w3.y, w3.z, w3.w};
  const float* pa = xg + (size_t)b * SEQ * (2 * DINNER) + d4;
  const float* pg = pa + DINNER;
  int t0 = tc * 8;
  float4 sA = {0.f, 0.f, 0.f, 0.f}, sB = sA, sC = sA;
  auto gated = [&](int t) {
    float4 a = *(const float4*)(pa + (size_t)t * (2 * DINNER));
    float4 g = *(const float4*)(pg + (size_t)t * (2 * DINNER));
    float4 r;
    r.x = a.x * (g.x / (1.f + __expf(-g.x)));
    r.y = a.y * (g.y / (1.f + __expf(-g.y)));
    r.z = a.z * (g.z / (1.f + __expf(-g.z)));
    r.w = a.w * (g.w / (1.f + __expf(-g.w)));
    return r;
  };
  if (t0 > 0) {
    sA = gated(t0 - 3);
    sB = gated(t0 - 2);
    sC = gated(t0 - 1);
  }
#pragma unroll
  for (int j = 0; j < 8; ++j) {
    int t = t0 + j;
    float4 sD = gated(t);
    float4 o;
    o.x = sA.x * wj0[0] + sB.x * wj0[1] + sC.x * wj0[2] + sD.x * wj0[3];
    o.y = sA.y * wj1[0] + sB.y * wj1[1] + sC.y * wj1[2] + sD.y * wj1[3];
    o.z = sA.z * wj2[0] + sB.z * wj2[1] + sC.z * wj2[2] + sD.z * wj2[3];
    o.w = sA.w * wj3[0] + sB.w * wj3[1] + sC.w * wj3[2] + sD.w * wj3[3];
    ushort4 ob = {f2bf(o.x), f2bf(o.y), f2bf(o.z), f2bf(o.w)};
    *(ushort4*)(xcbf + tiled_off(b * SEQ + t, d4, 64)) = ob;
    sA = sB; sB = sC; sC = sD;
  }
}

__global__ __launch_bounds__(256) void scan_local_k(const float* __restrict__ dt,
                                                    const unsigned short* __restrict__ xcbf,
                                                    const float* __restrict__ Bm,
                                                    const float* __restrict__ A,
                                                    float* __restrict__ hfin,
                                                    float* __restrict__ P) {
  int d = blockIdx.x * 256 + threadIdx.x;
  int c = blockIdx.y, b = blockIdx.z;
  float a[DSTATE], h[DSTATE];
#pragma unroll
  for (int s = 0; s < DSTATE; ++s) { a[s] = A[(size_t)d * DSTATE + s]; h[s] = 0.f; }
  float sdt = 0.f;
  int t0 = c * CLEN;
  for (int t = t0; t < t0 + CLEN; ++t) {
    size_t ro = (size_t)(b * SEQ + t);
    float dtv = dt[ro * DINNER + d];
    float xv = bf2f(xcbf[tiled_off((int)ro, d, 64)]);
    sdt += dtv;
    float bx = dtv * xv;
    float4 q0 = *(const float4*)(Bm + ro * DSTATE + 0);
    float4 q1 = *(const float4*)(Bm + ro * DSTATE + 4);
    float4 q2 = *(const float4*)(Bm + ro * DSTATE + 8);
    float4 q3 = *(const float4*)(Bm + ro * DSTATE + 12);
    float bm[DSTATE] = {q0.x, q0.y, q0.z, q0.w, q1.x, q1.y, q1.z, q1.w,
                        q2.x, q2.y, q2.z, q2.w, q3.x, q3.y, q3.z, q3.w};
#pragma unroll
    for (int s = 0; s < DSTATE; ++s) {
      float av = __expf(a[s] * dtv);
      h[s] = fmaf(av, h[s], bx * bm[s]);
    }
  }
  size_t o = ((size_t)(b * NCHUNK + c) * DINNER + d) * DSTATE;
#pragma unroll
  for (int s = 0; s < DSTATE; ++s) {
    hfin[o + s] = h[s];
    P[o + s] = __expf(a[s] * sdt);
  }
}

// In-place: hp holds hfin on entry, Hprev (state entering chunk c) on exit.
__global__ __launch_bounds__(256) void scan_chunks_k(float* hp, const float* __restrict__ P) {
  int j = blockIdx.x * 256 + threadIdx.x;
  int b = j / (DINNER * DSTATE);
  int r = j % (DINNER * DSTATE);
  float H = 0.f;
  for (int c = 0; c < NCHUNK; ++c) {
    size_t o = ((size_t)(b * NCHUNK + c) * DINNER * DSTATE) + r;
    float hf = hp[o];
    float pv = P[o];
    hp[o] = H;
    H = fmaf(pv, H, hf);
  }
}

__global__ __launch_bounds__(256) void scan_final_k(const float* __restrict__ dt,
                                                    const unsigned short* __restrict__ xcbf,
                                                    const float* __restrict__ Bm,
                                                    const float* __restrict__ Cm,
                                                    const float* __restrict__ A,
                                                    const float* __restrict__ Hprev,
                                                    const float* __restrict__ Dskip,
                                                    unsigned short* __restrict__ ysbf) {
  int d = blockIdx.x * 256 + threadIdx.x;
  int c = blockIdx.y, b = blockIdx.z;
  float a[DSTATE], h[DSTATE];
  size_t ho = ((size_t)(b * NCHUNK + c) * DINNER + d) * DSTATE;
#pragma unroll
  for (int s = 0; s < DSTATE; ++s) {
    a[s] = A[(size_t)d * DSTATE + s];
    h[s] = Hprev[ho + s];
  }
  float Dv = Dskip[d];
  int t0 = c * CLEN;
  for (int t = t0; t < t0 + CLEN; ++t) {
    size_t ro = (size_t)(b * SEQ + t);
    float dtv = dt[ro * DINNER + d];
    float xv = bf2f(xcbf[tiled_off((int)ro, d, 64)]);
    float bx = dtv * xv;
    float4 q0 = *(const float4*)(Bm + ro * DSTATE + 0);
    float4 q1 = *(const float4*)(Bm + ro * DSTATE + 4);
    float4 q2 = *(const float4*)(Bm + ro * DSTATE + 8);
    float4 q3 = *(const float4*)(Bm + ro * DSTATE + 12);
    float bm[DSTATE] = {q0.x, q0.y, q0.z, q0.w, q1.x, q1.y, q1.z, q1.w,
                        q2.x, q2.y, q2.z, q2.w, q3.x, q3.y, q3.z, q3.w};
    float4 r0 = *(const float4*)(Cm + ro * DSTATE + 0);
    float4 r1 = *(const float4*)(Cm + ro * DSTATE + 4);
    float4 r2 = *(const float4*)(Cm + ro * DSTATE + 8);
    float4 r3 = *(const float4*)(Cm + ro * DSTATE + 12);
    float cm[DSTATE] = {r0.x, r0.y, r0.z, r0.w, r1.x, r1.y, r1.z, r1.w,
                        r2.x, r2.y, r2.z, r2.w, r3.x, r3.y, r3.z, r3.w};
    float y = Dv * xv;
#pragma unroll
    for (int s = 0; s < DSTATE; ++s) {
      float av = __expf(a[s] * dtv);
      h[s] = fmaf(av, h[s], bx * bm[s]);
      y = fmaf(h[s], cm[s], y);
    }
    ysbf[tiled_off((int)ro, d, 64)] = f2bf(y);
  }
}

extern "C" void kernel_launch(void* const* d_in, const int* in_sizes, int n_in,
                              void* d_out, int out_size, void* d_ws, size_t ws_size,
                              hipStream_t stream) {
  (void)in_sizes; (void)n_in; (void)out_size; (void)ws_size;
  const float* x       = (const float*)d_in[0];
  const float* norm_w  = (const float*)d_in[1];
  const float* in_proj = (const float*)d_in[2];
  const float* conv_w  = (const float*)d_in[3];
  const float* dt_w    = (const float*)d_in[4];
  const float* dt_b    = (const float*)d_in[5];
  const float* A_log   = (const float*)d_in[6];
  const float* B_w     = (const float*)d_in[7];
  const float* C_w     = (const float*)d_in[8];
  const float* D_skip  = (const float*)d_in[9];
  const float* out_w   = (const float*)d_in[10];
  float* out = (float*)d_out;
  float* ws = (float*)d_ws;

  // Workspace (f32 units), lifetime-aliased:
  float* Aneg = ws;                  // 32768
  float* Bm   = ws + 32768;
  float* Cm   = ws + 65536;
  float* b0   = ws + 98304;
  float* xg   = b0;                  // 8M f32 (steps 4-5)
  float* dtb  = b0;                  // 4M (7-10, xg dead)
  float* hfin = b0 + 4194304;        // 2M (8-10; becomes Hprev in-place)
  float* Pbuf = b0 + 6291456;        // 2M (8-9)
  unsigned short* xc_bf = (unsigned short*)(b0 + 8388608);   // 4M shorts (5-10)
  unsigned short* ys_bf = (unsigned short*)(b0 + 10485760);  // 4M shorts (10-12)
  float* Rw   = b0 + 12582912;       // in_wT(2-4) -> W2t(6-7) -> out_wT(11-12)
  unsigned short* in_wT  = (unsigned short*)Rw;
  unsigned short* W2t    = (unsigned short*)Rw;
  unsigned short* out_wT = (unsigned short*)Rw;
  unsigned short* xn_bf  = (unsigned short*)(b0 + 14745600); // 2M shorts (3-4)

  init_aneg_k<<<dim3(DINNER * DSTATE / 256), dim3(256), 0, stream>>>(A_log, Aneg);
  transpose_cvt_k<<<dim3(2 * DINNER / 32, DMODEL / 32), dim3(32, 8), 0, stream>>>(
      in_proj, in_wT, DMODEL, 2 * DINNER);
  rmsnorm_k<<<dim3(NTOK), dim3(256), 0, stream>>>(x, norm_w, xn_bf);
  gemm_bf16_t<128, 128, 0><<<dim3(2 * DINNER / 128, NTOK / 128), dim3(256), 0, stream>>>(
      xn_bf, in_wT, xg, NTOK, 2 * DINNER, DMODEL, 2 * DINNER, nullptr, nullptr, nullptr);
  siluconv_k<<<dim3(NTOK * (DINNER / 4) / 8 / 256), dim3(256), 0, stream>>>(
      xg, conv_w, xc_bf);
  build_w2t_k<<<dim3(DINNER / 32, NEXT / 32), dim3(32, 8), 0, stream>>>(
      dt_w, B_w, C_w, W2t);
  gemm_bf16_t<128, 64, 2><<<dim3(NEXT / 64, NTOK / 128), dim3(256), 0, stream>>>(
      xc_bf, W2t, dtb, NTOK, NEXT, DINNER, DINNER, dt_b, Bm, Cm);
  scan_local_k<<<dim3(DINNER / 256, NCHUNK, BATCH), dim3(256), 0, stream>>>(
      dtb, xc_bf, Bm, Aneg, hfin, Pbuf);
  scan_chunks_k<<<dim3(BATCH * DINNER * DSTATE / 256), dim3(256), 0, stream>>>(
      hfin, Pbuf);
  scan_final_k<<<dim3(DINNER / 256, NCHUNK, BATCH), dim3(256), 0, stream>>>(
      dtb, xc_bf, Bm, Cm, Aneg, hfin, D_skip, ys_bf);
  transpose_cvt_k<<<dim3(DMODEL / 32, DINNER / 32), dim3(32, 8), 0, stream>>>(
      out_w, out_wT, DINNER, DMODEL);
  gemm_bf16_t<64, 64, 0><<<dim3(DMODEL / 64, NTOK / 64), dim3(256), 0, stream>>>(
      ys_bf, out_wT, out, NTOK, DMODEL, DINNER, DMODEL, nullptr, nullptr, nullptr);
}

// Round 8
// 174.252 us; speedup vs baseline: 1.4219x; 1.0257x over previous
//
#include <hip/hip_runtime.h>
#include <cmath>

// SSM forward, round 8: 8-wave GEMM blocks (16 waves/CU), m-fastest XCD column-strip
// swizzle (B weights L2-resident per XCD), bf16 xg. Counted-vmcnt 2-deep pipeline,
// fragment-tiled operands, BK=64.

#define SEQ    1024
#define BATCH  2
#define DMODEL 1024
#define DINNER 2048
#define DSTATE 16
#define NTOK   (BATCH * SEQ)
#define NCHUNK 32
#define CLEN   32
#define NEXT   2112  // DINNER + 16 + 16 + 32 pad (64-multiple)

typedef __attribute__((ext_vector_type(8))) short short8;
typedef __attribute__((ext_vector_type(4))) float f32x4;

__device__ __forceinline__ unsigned short f2bf(float f) {
  unsigned int u = __float_as_uint(f);
  unsigned int r = (u + 0x7fffu + ((u >> 16) & 1u)) >> 16;
  return (unsigned short)r;
}
__device__ __forceinline__ float bf2f(unsigned short v) {
  return __uint_as_float((unsigned int)v << 16);
}
__device__ __forceinline__ float softplus_f(float x) {
  return (x > 20.f) ? x : log1pf(__expf(x));
}
__device__ __forceinline__ void gload_lds16(const void* g, void* l) {
  __builtin_amdgcn_global_load_lds(
      (const __attribute__((address_space(1))) unsigned int*)g,
      (__attribute__((address_space(3))) unsigned int*)l, 16, 0, 0);
}

template <int N>
__device__ __forceinline__ void wait_vmcnt() {
  if constexpr (N <= 0)      asm volatile("s_waitcnt vmcnt(0)" ::: "memory");
  else if constexpr (N == 1) asm volatile("s_waitcnt vmcnt(1)" ::: "memory");
  else if constexpr (N == 2) asm volatile("s_waitcnt vmcnt(2)" ::: "memory");
  else if constexpr (N == 3) asm volatile("s_waitcnt vmcnt(3)" ::: "memory");
  else if constexpr (N == 4) asm volatile("s_waitcnt vmcnt(4)" ::: "memory");
  else if constexpr (N == 5) asm volatile("s_waitcnt vmcnt(5)" ::: "memory");
  else if constexpr (N == 6) asm volatile("s_waitcnt vmcnt(6)" ::: "memory");
  else                       asm volatile("s_waitcnt vmcnt(8)" ::: "memory");
}

// Fragment-tiled layout: element (row, k) of a [R][K] bf16 matrix lives at
// short index: block(row>>4, k>>5)*512 + lane(row&15, (k>>3)&3)*8 + (k&7).
__device__ __forceinline__ size_t tiled_off(int row, int k, int kblks) {
  return ((size_t)(row >> 4) * kblks + (k >> 5)) * 512
       + ((size_t)((row & 15) + (((k >> 3) & 3) << 4)) << 3) + (k & 7);
}

__global__ __launch_bounds__(256) void init_aneg_k(const float* __restrict__ A_log,
                                                   float* __restrict__ Aneg) {
  int i = blockIdx.x * 256 + threadIdx.x;
  Aneg[i] = -__expf(A_log[i]);
}

// W[K][N] f32 -> tiled bf16 (rows = n, reduction = k).
__global__ void transpose_cvt_k(const float* __restrict__ W, unsigned short* __restrict__ Wt,
                                int K, int N) {
  __shared__ float tile[32][33];
  int k0 = blockIdx.y * 32, n0 = blockIdx.x * 32;
  int tx = threadIdx.x, ty = threadIdx.y;  // 32 x 8
  int kblks = K >> 5;
#pragma unroll
  for (int i = 0; i < 32; i += 8)
    tile[ty + i][tx] = W[(size_t)(k0 + ty + i) * N + n0 + tx];
  __syncthreads();
#pragma unroll
  for (int i = 0; i < 32; i += 8)
    Wt[tiled_off(n0 + ty + i, k0 + tx, kblks)] = f2bf(tile[tx][ty + i]);
}

// Combined dt|B|C weight, tiled: rows [0,2048)=dt_w^T, [2048,2064)=B_w^T,
// [2064,2080)=C_w^T, [2080,2112)=0. kblks = 64.
__global__ void build_w2t_k(const float* __restrict__ dt_w, const float* __restrict__ B_w,
                            const float* __restrict__ C_w, unsigned short* __restrict__ Wt) {
  __shared__ float tile[32][33];
  int k0 = blockIdx.x * 32, n0 = blockIdx.y * 32;
  int tx = threadIdx.x, ty = threadIdx.y;  // 32 x 8
  if (n0 < DINNER) {
#pragma unroll
    for (int i = 0; i < 32; i += 8)
      tile[ty + i][tx] = dt_w[(size_t)(k0 + ty + i) * DINNER + n0 + tx];
    __syncthreads();
#pragma unroll
    for (int i = 0; i < 32; i += 8)
      Wt[tiled_off(n0 + ty + i, k0 + tx, 64)] = f2bf(tile[tx][ty + i]);
  } else {
#pragma unroll
    for (int i = 0; i < 32; i += 8) {
      int n = n0 + ty + i;
      float v = 0.f;
      if (n < DINNER + 16) v = B_w[(size_t)(k0 + tx) * DSTATE + (n - DINNER)];
      else if (n < DINNER + 32) v = C_w[(size_t)(k0 + tx) * DSTATE + (n - DINNER - 16)];
      Wt[tiled_off(n, k0 + tx, 64)] = f2bf(v);
    }
  }
}

__global__ __launch_bounds__(256) void rmsnorm_k(const float* __restrict__ x,
                                                 const float* __restrict__ w,
                                                 unsigned short* __restrict__ xnbf) {
  int row = blockIdx.x, tid = threadIdx.x;
  const float4 v = *(const float4*)(x + (size_t)row * DMODEL + tid * 4);
  float ss = v.x * v.x + v.y * v.y + v.z * v.z + v.w * v.w;
#pragma unroll
  for (int off = 32; off > 0; off >>= 1) ss += __shfl_down(ss, off);
  __shared__ float red[4];
  if ((tid & 63) == 0) red[tid >> 6] = ss;
  __syncthreads();
  float tot = red[0] + red[1] + red[2] + red[3];
  float scale = rsqrtf(tot * (1.0f / DMODEL) + 1e-6f);
  const float4 wv = *(const float4*)(w + tid * 4);
  ushort4 o;
  o.x = f2bf(v.x * scale * wv.x);
  o.y = f2bf(v.y * scale * wv.y);
  o.z = f2bf(v.z * scale * wv.z);
  o.w = f2bf(v.w * scale * wv.w);
  *(ushort4*)(xnbf + tiled_off(row, tid * 4, DMODEL / 32)) = o;
}

// C = A @ Bt^T, operands fragment-TILED bf16. BK=64, WM x WN waves.
// 2-deep counted-vmcnt pipeline. m-fastest XCD column-strip swizzle.
// MODE 0: f32 C. MODE 1: bf16 C. MODE 2: dt|B|C combined epilogue (f32).
template <int BM, int BN, int WM, int WN, int MODE>
__global__ __launch_bounds__(WM * WN * 64) void gemm_bf16_t(
    const unsigned short* __restrict__ At, const unsigned short* __restrict__ Btt,
    void* __restrict__ Cv, int M, int N, int K, int ldc,
    const float* __restrict__ bias, float* __restrict__ Bm, float* __restrict__ Cm) {
  constexpr int NW = WM * WN;
  constexpr int WTM = BM / WM, WTN = BN / WN;
  constexpr int FM = WTM / 16, FN = WTN / 16;
  constexpr int ASUB = BM / 16, BSUB = BN / 16;     // subtiles per kblk
  constexpr int ALOAD = ASUB * 2, BLOAD = BSUB * 2; // per K-step (2 kblks)
  constexpr int LPW = (ALOAD + BLOAD) / NW;         // loads per wave per stage
  static_assert(ALOAD % NW == 0 && BLOAD % NW == 0, "uniform load split");
  __shared__ __align__(16) unsigned short Abuf[2][BM * 64];
  __shared__ __align__(16) unsigned short Bbuf[2][BN * 64];
  const int tid = threadIdx.x;
  const int wave = tid >> 6, lane = tid & 63;

  // m-fastest XCD swizzle: each XCD owns a contiguous n-column strip.
  int lin = blockIdx.x + blockIdx.y * gridDim.x;
  int nwg = gridDim.x * gridDim.y;
  int swz = (lin & 7) * (nwg >> 3) + (lin >> 3);
  const int MT = gridDim.y;
  const int bm = (swz % MT) * BM, bn = (swz / MT) * BN;

  const int wm = wave / WN, wn = wave % WN;
  const int kblks = K >> 5;
  const unsigned short* Ag = At + ((size_t)(bm >> 4) * kblks) * 512 + (lane << 3);
  const unsigned short* Bg = Btt + ((size_t)(bn >> 4) * kblks) * 512 + (lane << 3);

  auto stage = [&](int buf, int t) {
#pragma unroll
    for (int i = wave; i < ALOAD; i += NW) {
      int s = i >> 1, kk = i & 1;
      gload_lds16(Ag + ((size_t)s * kblks + 2 * t + kk) * 512,
                  &Abuf[buf][(kk * ASUB + s) * 512]);
    }
#pragma unroll
    for (int i = wave; i < BLOAD; i += NW) {
      int s = i >> 1, kk = i & 1;
      gload_lds16(Bg + ((size_t)s * kblks + 2 * t + kk) * 512,
                  &Bbuf[buf][(kk * BSUB + s) * 512]);
    }
  };

  f32x4 acc[FM][FN] = {};
  const int nt = K / 64;
  stage(0, 0);
  stage(1, 1);
  for (int t = 0; t < nt; ++t) {
    const int cur = t & 1;
    if (t + 1 < nt) wait_vmcnt<LPW>();  // tile-t loads landed; t+1 stays in flight
    else            wait_vmcnt<0>();
    __builtin_amdgcn_s_barrier();       // whole tile t visible in LDS
    short8 af[2][FM], bfr[2][FN];
#pragma unroll
    for (int kk = 0; kk < 2; ++kk) {
#pragma unroll
      for (int m = 0; m < FM; ++m)
        af[kk][m] = *(const short8*)&Abuf[cur][(kk * ASUB + wm * FM + m) * 512 + (lane << 3)];
#pragma unroll
      for (int n = 0; n < FN; ++n)
        bfr[kk][n] = *(const short8*)&Bbuf[cur][(kk * BSUB + wn * FN + n) * 512 + (lane << 3)];
    }
    asm volatile("s_waitcnt lgkmcnt(0)" ::: "memory");
    __builtin_amdgcn_sched_barrier(0);
    __builtin_amdgcn_s_barrier();       // all waves done reading buf[cur]
    if (t + 2 < nt) stage(cur, t + 2);  // overwrite is now safe
#pragma unroll
    for (int kk = 0; kk < 2; ++kk)
#pragma unroll
      for (int m = 0; m < FM; ++m)
#pragma unroll
        for (int n = 0; n < FN; ++n)
          acc[m][n] = __builtin_amdgcn_mfma_f32_16x16x32_bf16(af[kk][m], bfr[kk][n],
                                                              acc[m][n], 0, 0, 0);
  }

  const int rbase = bm + wm * WTM + (lane >> 4) * 4;
  const int cbase = bn + wn * WTN + (lane & 15);
#pragma unroll
  for (int m = 0; m < FM; ++m)
#pragma unroll
    for (int n = 0; n < FN; ++n) {
      int col = cbase + n * 16;
#pragma unroll
      for (int r = 0; r < 4; ++r) {
        int row = rbase + m * 16 + r;
        float v = acc[m][n][r];
        if (MODE == 0) {
          ((float*)Cv)[(size_t)row * ldc + col] = v;
        } else if (MODE == 1) {
          ((unsigned short*)Cv)[(size_t)row * ldc + col] = f2bf(v);
        } else {  // MODE 2 (dt | B | C combined)
          if (col < DINNER)
            ((float*)Cv)[(size_t)row * DINNER + col] = softplus_f(v + bias[col]);
          else if (col < DINNER + 16)
            Bm[(size_t)row * DSTATE + (col - DINNER)] = v;
          else if (col < DINNER + 32)
            Cm[(size_t)row * DSTATE + (col - DINNER - 16)] = v;
        }
      }
    }
}

// Fused: x_inner = a * silu(g) (bf16 xg), causal depthwise conv width 4; TILED bf16 out.
__global__ __launch_bounds__(256) void siluconv_k(const unsigned short* __restrict__ xg,
                                                  const float* __restrict__ w,
                                                  unsigned short* __restrict__ xcbf) {
  int idx = blockIdx.x * 256 + threadIdx.x;
  int d4 = (idx & 511) << 2;
  int tc = (idx >> 9) & 127;
  int b = idx >> 16;
  float4 w0 = *(const float4*)(w + (d4 + 0) * 4);
  float4 w1 = *(const float4*)(w + (d4 + 1) * 4);
  float4 w2 = *(const float4*)(w + (d4 + 2) * 4);
  float4 w3 = *(const float4*)(w + (d4 + 3) * 4);
  const float wj0[4] = {w0.x, w0.y, w0.z, w0.w};
  const float wj1[4] = {w1.x, w1.y, w1.z, w1.w};
  const float wj2[4] = {w2.x, w2.y, w2.z, w2.w};
  const float wj3[4] = {w3.x, w3.y, w3.z, w3.w};
  const unsigned short* pa = xg + (size_t)b * SEQ * (2 * DINNER) + d4;
  const unsigned short* pg = pa + DINNER;
  int t0 = tc * 8;
  float4 sA = {0.f, 0.f, 0.f, 0.f}, sB = sA, sC = sA;
  auto gated = [&](int t) {
    ushort4 av = *(const ushort4*)(pa + (size_t)t * (2 * DINNER));
    ushort4 gv = *(const ushort4*)(pg + (size_t)t * (2 * DINNER));
    float4 r;
    float gx = bf2f(gv.x), gy = bf2f(gv.y), gz = bf2f(gv.z), gw = bf2f(gv.w);
    r.x = bf2f(av.x) * (gx / (1.f + __expf(-gx)));
    r.y = bf2f(av.y) * (gy / (1.f + __expf(-gy)));
    r.z = bf2f(av.z) * (gz / (1.f + __expf(-gz)));
    r.w = bf2f(av.w) * (gw / (1.f + __expf(-gw)));
    return r;
  };
  if (t0 > 0) {
    sA = gated(t0 - 3);
    sB = gated(t0 - 2);
    sC = gated(t0 - 1);
  }
#pragma unroll
  for (int j = 0; j < 8; ++j) {
    int t = t0 + j;
    float4 sD = gated(t);
    float4 o;
    o.x = sA.x * wj0[0] + sB.x * wj0[1] + sC.x * wj0[2] + sD.x * wj0[3];
    o.y = sA.y * wj1[0] + sB.y * wj1[1] + sC.y * wj1[2] + sD.y * wj1[3];
    o.z = sA.z * wj2[0] + sB.z * wj2[1] + sC.z * wj2[2] + sD.z * wj2[3];
    o.w = sA.w * wj3[0] + sB.w * wj3[1] + sC.w * wj3[2] + sD.w * wj3[3];
    ushort4 ob = {f2bf(o.x), f2bf(o.y), f2bf(o.z), f2bf(o.w)};
    *(ushort4*)(xcbf + tiled_off(b * SEQ + t, d4, 64)) = ob;
    sA = sB; sB = sC; sC = sD;
  }
}

__global__ __launch_bounds__(256) void scan_local_k(const float* __restrict__ dt,
                                                    const unsigned short* __restrict__ xcbf,
                                                    const float* __restrict__ Bm,
                                                    const float* __restrict__ A,
                                                    float* __restrict__ hfin,
                                                    float* __restrict__ P) {
  int d = blockIdx.x * 256 + threadIdx.x;
  int c = blockIdx.y, b = blockIdx.z;
  float a[DSTATE], h[DSTATE];
#pragma unroll
  for (int s = 0; s < DSTATE; ++s) { a[s] = A[(size_t)d * DSTATE + s]; h[s] = 0.f; }
  float sdt = 0.f;
  int t0 = c * CLEN;
  for (int t = t0; t < t0 + CLEN; ++t) {
    size_t ro = (size_t)(b * SEQ + t);
    float dtv = dt[ro * DINNER + d];
    float xv = bf2f(xcbf[tiled_off((int)ro, d, 64)]);
    sdt += dtv;
    float bx = dtv * xv;
    float4 q0 = *(const float4*)(Bm + ro * DSTATE + 0);
    float4 q1 = *(const float4*)(Bm + ro * DSTATE + 4);
    float4 q2 = *(const float4*)(Bm + ro * DSTATE + 8);
    float4 q3 = *(const float4*)(Bm + ro * DSTATE + 12);
    float bm[DSTATE] = {q0.x, q0.y, q0.z, q0.w, q1.x, q1.y, q1.z, q1.w,
                        q2.x, q2.y, q2.z, q2.w, q3.x, q3.y, q3.z, q3.w};
#pragma unroll
    for (int s = 0; s < DSTATE; ++s) {
      float av = __expf(a[s] * dtv);
      h[s] = fmaf(av, h[s], bx * bm[s]);
    }
  }
  size_t o = ((size_t)(b * NCHUNK + c) * DINNER + d) * DSTATE;
#pragma unroll
  for (int s = 0; s < DSTATE; ++s) {
    hfin[o + s] = h[s];
    P[o + s] = __expf(a[s] * sdt);
  }
}

// In-place: hp holds hfin on entry, Hprev (state entering chunk c) on exit.
__global__ __launch_bounds__(256) void scan_chunks_k(float* hp, const float* __restrict__ P) {
  int j = blockIdx.x * 256 + threadIdx.x;
  int b = j / (DINNER * DSTATE);
  int r = j % (DINNER * DSTATE);
  float H = 0.f;
  for (int c = 0; c < NCHUNK; ++c) {
    size_t o = ((size_t)(b * NCHUNK + c) * DINNER * DSTATE) + r;
    float hf = hp[o];
    float pv = P[o];
    hp[o] = H;
    H = fmaf(pv, H, hf);
  }
}

__global__ __launch_bounds__(256) void scan_final_k(const float* __restrict__ dt,
                                                    const unsigned short* __restrict__ xcbf,
                                                    const float* __restrict__ Bm,
                                                    const float* __restrict__ Cm,
                                                    const float* __restrict__ A,
                                                    const float* __restrict__ Hprev,
                                                    const float* __restrict__ Dskip,
                                                    unsigned short* __restrict__ ysbf) {
  int d = blockIdx.x * 256 + threadIdx.x;
  int c = blockIdx.y, b = blockIdx.z;
  float a[DSTATE], h[DSTATE];
  size_t ho = ((size_t)(b * NCHUNK + c) * DINNER + d) * DSTATE;
#pragma unroll
  for (int s = 0; s < DSTATE; ++s) {
    a[s] = A[(size_t)d * DSTATE + s];
    h[s] = Hprev[ho + s];
  }
  float Dv = Dskip[d];
  int t0 = c * CLEN;
  for (int t = t0; t < t0 + CLEN; ++t) {
    size_t ro = (size_t)(b * SEQ + t);
    float dtv = dt[ro * DINNER + d];
    float xv = bf2f(xcbf[tiled_off((int)ro, d, 64)]);
    float bx = dtv * xv;
    float4 q0 = *(const float4*)(Bm + ro * DSTATE + 0);
    float4 q1 = *(const float4*)(Bm + ro * DSTATE + 4);
    float4 q2 = *(const float4*)(Bm + ro * DSTATE + 8);
    float4 q3 = *(const float4*)(Bm + ro * DSTATE + 12);
    float bm[DSTATE] = {q0.x, q0.y, q0.z, q0.w, q1.x, q1.y, q1.z, q1.w,
                        q2.x, q2.y, q2.z, q2.w, q3.x, q3.y, q3.z, q3.w};
    float4 r0 = *(const float4*)(Cm + ro * DSTATE + 0);
    float4 r1 = *(const float4*)(Cm + ro * DSTATE + 4);
    float4 r2 = *(const float4*)(Cm + ro * DSTATE + 8);
    float4 r3 = *(const float4*)(Cm + ro * DSTATE + 12);
    float cm[DSTATE] = {r0.x, r0.y, r0.z, r0.w, r1.x, r1.y, r1.z, r1.w,
                        r2.x, r2.y, r2.z, r2.w, r3.x, r3.y, r3.z, r3.w};
    float y = Dv * xv;
#pragma unroll
    for (int s = 0; s < DSTATE; ++s) {
      float av = __expf(a[s] * dtv);
      h[s] = fmaf(av, h[s], bx * bm[s]);
      y = fmaf(h[s], cm[s], y);
    }
    ysbf[tiled_off((int)ro, d, 64)] = f2bf(y);
  }
}

extern "C" void kernel_launch(void* const* d_in, const int* in_sizes, int n_in,
                              void* d_out, int out_size, void* d_ws, size_t ws_size,
                              hipStream_t stream) {
  (void)in_sizes; (void)n_in; (void)out_size; (void)ws_size;
  const float* x       = (const float*)d_in[0];
  const float* norm_w  = (const float*)d_in[1];
  const float* in_proj = (const float*)d_in[2];
  const float* conv_w  = (const float*)d_in[3];
  const float* dt_w    = (const float*)d_in[4];
  const float* dt_b    = (const float*)d_in[5];
  const float* A_log   = (const float*)d_in[6];
  const float* B_w     = (const float*)d_in[7];
  const float* C_w     = (const float*)d_in[8];
  const float* D_skip  = (const float*)d_in[9];
  const float* out_w   = (const float*)d_in[10];
  float* out = (float*)d_out;
  float* ws = (float*)d_ws;

  // Workspace (f32 units), lifetime-aliased:
  float* Aneg = ws;                  // 32768
  float* Bm   = ws + 32768;
  float* Cm   = ws + 65536;
  float* b0   = ws + 98304;
  unsigned short* xg = (unsigned short*)b0;                  // 8M shorts = 4M f32 (4-5)
  float* dtb  = b0;                  // 4M f32 (7-10, xg dead after siluconv... see note
  // NOTE: xg (4M f32 worth) and dtb (4M) overlap in time? xg dead after siluconv(5);
  // dtb written at step 7. Safe.
  float* hfin = b0 + 4194304;        // 2M (8-10; becomes Hprev in-place)
  float* Pbuf = b0 + 6291456;        // 2M (8-9)
  unsigned short* xc_bf = (unsigned short*)(b0 + 8388608);   // 4M shorts (5-10)
  unsigned short* ys_bf = (unsigned short*)(b0 + 10485760);  // 4M shorts (10-12)
  float* Rw   = b0 + 12582912;       // in_wT(2-4) -> W2t(6-7) -> out_wT(11-12)
  unsigned short* in_wT  = (unsigned short*)Rw;
  unsigned short* W2t    = (unsigned short*)Rw;
  unsigned short* out_wT = (unsigned short*)Rw;
  unsigned short* xn_bf  = (unsigned short*)(b0 + 14745600); // 2M shorts (3-4)

  init_aneg_k<<<dim3(DINNER * DSTATE / 256), dim3(256), 0, stream>>>(A_log, Aneg);
  transpose_cvt_k<<<dim3(2 * DINNER / 32, DMODEL / 32), dim3(32, 8), 0, stream>>>(
      in_proj, in_wT, DMODEL, 2 * DINNER);
  rmsnorm_k<<<dim3(NTOK), dim3(256), 0, stream>>>(x, norm_w, xn_bf);
  // in_proj: 128x128, 8 waves (2x4), MODE 1 (bf16 xg)
  gemm_bf16_t<128, 128, 2, 4, 1><<<dim3(2 * DINNER / 128, NTOK / 128), dim3(512), 0, stream>>>(
      xn_bf, in_wT, xg, NTOK, 2 * DINNER, DMODEL, 2 * DINNER, nullptr, nullptr, nullptr);
  siluconv_k<<<dim3(NTOK * (DINNER / 4) / 8 / 256), dim3(256), 0, stream>>>(
      xg, conv_w, xc_bf);
  build_w2t_k<<<dim3(DINNER / 32, NEXT / 32), dim3(32, 8), 0, stream>>>(
      dt_w, B_w, C_w, W2t);
  // dt: 128x64, 8 waves (4x2), MODE 2
  gemm_bf16_t<128, 64, 4, 2, 2><<<dim3(NEXT / 64, NTOK / 128), dim3(512), 0, stream>>>(
      xc_bf, W2t, dtb, NTOK, NEXT, DINNER, DINNER, dt_b, Bm, Cm);
  scan_local_k<<<dim3(DINNER / 256, NCHUNK, BATCH), dim3(256), 0, stream>>>(
      dtb, xc_bf, Bm, Aneg, hfin, Pbuf);
  scan_chunks_k<<<dim3(BATCH * DINNER * DSTATE / 256), dim3(256), 0, stream>>>(
      hfin, Pbuf);
  scan_final_k<<<dim3(DINNER / 256, NCHUNK, BATCH), dim3(256), 0, stream>>>(
      dtb, xc_bf, Bm, Cm, Aneg, hfin, D_skip, ys_bf);
  transpose_cvt_k<<<dim3(DMODEL / 32, DINNER / 32), dim3(32, 8), 0, stream>>>(
      out_w, out_wT, DINNER, DMODEL);
  // out_proj: 64x32, 4 waves (2x2), MODE 0
  gemm_bf16_t<64, 32, 2, 2, 0><<<dim3(DMODEL / 32, NTOK / 64), dim3(256), 0, stream>>>(
      ys_bf, out_wT, out, NTOK, DMODEL, DINNER, DMODEL, nullptr, nullptr, nullptr);
}